// Round 5
// baseline (2958.538 us; speedup 1.0000x reference)
//
#include <hip/hip_runtime.h>
#include <hip/hip_fp16.h>

typedef unsigned int u32;
typedef unsigned short u16;
typedef _Float16 half2v __attribute__((ext_vector_type(2)));

#define N_UNITS 512
#define N_ORDER 256
#define N_T     1024
#define N_B     64
#define KWG     4
#define PKT_STRIDE 288   // dwords per (parity,b,q) packet: 128 m + 128 h + 6 u

__device__ inline float dot2f(u32 a, u32 b, float acc) {
    return __builtin_amdgcn_fdot2(__builtin_bit_cast(half2v, a),
                                  __builtin_bit_cast(half2v, b), acc, false);
}
__device__ inline u16 f2h_bits(float v) {
    _Float16 f = (_Float16)v;
    return __builtin_bit_cast(u16, f);
}
__device__ inline float hbits2f(u32 dw) {
    u16 s = (u16)(dw & 0xFFFFu);
    _Float16 f = __builtin_bit_cast(_Float16, s);
    return (float)f;
}
__device__ inline u32 pack_h2(float a, float b) {
    return (u32)f2h_bits(a) | ((u32)f2h_bits(b) << 16);
}
__device__ inline u32 aload(const u32* p) {
    return __hip_atomic_load(p, __ATOMIC_RELAXED, __HIP_MEMORY_SCOPE_AGENT);
}
__device__ inline void astore(u32* p, u32 v) {
    __hip_atomic_store(p, v, __ATOMIC_RELAXED, __HIP_MEMORY_SCOPE_AGENT);
}
__device__ inline float tanh_fast(float x) {
    float xa = fminf(fmaxf(x, -12.f), 12.f);
    float e  = __expf(2.f * xa);
#if __has_builtin(__builtin_amdgcn_rcpf)
    return (e - 1.f) * __builtin_amdgcn_rcpf(e + 1.f);
#else
    return (e - 1.f) / (e + 1.f);
#endif
}

// hk2[kk][c] = half2(hk[2kk][c], hk[2kk+1][c]),  kk<256, c<512
__global__ __launch_bounds__(256)
void prep_hk(const float* __restrict__ hk, u32* __restrict__ hk2) {
    int tid = blockIdx.x * 256 + threadIdx.x;   // 131072 total
    int kk = tid >> 9, c = tid & 511;
    hk2[tid] = pack_h2(hk[(2 * kk) * 512 + c], hk[(2 * kk + 1) * 512 + c]);
}

// AMK = mk + AT@mk  (fp16, j-pair packed);  BMK = BT@mk (fp32)
__global__ __launch_bounds__(512)
void prep_amk(const float* __restrict__ mk, const float* __restrict__ at,
              const float* __restrict__ bt,
              u32* __restrict__ amk2, float* __restrict__ bmk) {
    int bj = blockIdx.x, c = threadIdx.x;
    if (bj < 128) {
        int j0 = 2 * bj, j1 = j0 + 1;
        float a0 = mk[j0 * 512 + c];
        float a1 = mk[j1 * 512 + c];
        #pragma unroll 8
        for (int k = 0; k < 256; ++k) {
            float w = mk[k * 512 + c];
            a0 = fmaf(at[j0 * 256 + k], w, a0);
            a1 = fmaf(at[j1 * 256 + k], w, a1);
        }
        amk2[bj * 512 + c] = pack_h2(a0, a1);
    } else {
        float s = 0.f;
        #pragma unroll 8
        for (int k = 0; k < 256; ++k) s = fmaf(bt[k], mk[k * 512 + c], s);
        bmk[c] = s;
    }
}

// K=4 WGs per batch; grid=256 (1 WG/CU). b=g&63, q=g>>6.
// Weights pinned in VGPRs (asm fence). State in LDS as dword-pairs; all hot
// LDS reads are uint4/float4 wave-broadcasts. 2 barriers/step, 1 packet
// exchange/step (self-validating epoch-tagged dwords, relaxed agent atomics).
__global__ __launch_bounds__(512, 2)
void lmu_main(const float* __restrict__ x, const float* __restrict__ ie,
              const float* __restrict__ he, const float* __restrict__ me,
              const float* __restrict__ ik, const float* __restrict__ bt,
              const float* __restrict__ at,
              const u32* __restrict__ hk2, const u32* __restrict__ amk2,
              const float* __restrict__ bmk,
              u32* __restrict__ pkt, float* __restrict__ out) {
    __shared__ float xs[N_T];
    __shared__ float he_sl[128], ik_sl[128], bmk_sl[128];
    __shared__ float me_sl[64], bt_sl[64];
    __shared__ __align__(16) u16 h_h16[N_UNITS];            // h fp16, k-order
    __shared__ __align__(16) u16 m_hi16[N_ORDER], m_lo16[N_ORDER];
    __shared__ __align__(16) float mf[N_ORDER];             // m fp32
    __shared__ __align__(16) float ufrag[12];               // u frags [q][w0..2]
    __shared__ float zbuf[512], ampart[512];

    const int tid = threadIdx.x;
    const int g   = blockIdx.x;
    const int b   = g & 63;
    const int q   = g >> 6;
    const int kg  = tid >> 7;        // 0..3  (z k-quarter; wave-uniform)
    const int cl  = tid & 127;
    const int kg8 = tid >> 6;        // 0..7  (AT k-eighth; wave-uniform)
    const int jl  = tid & 63;
    const int J   = 64 * q + jl;
    const int lane = tid & 63;

    // ---- preload LDS ----
    for (int i = tid; i < N_T; i += 512) xs[i] = x[b * N_T + i];
    if (tid < 128) {
        he_sl[tid]  = he[128 * q + tid];
        ik_sl[tid]  = ik[128 * q + tid];
        bmk_sl[tid] = bmk[128 * q + tid];
    }
    if (tid < 64) { me_sl[tid] = me[J]; bt_sl[tid] = bt[J]; }
    h_h16[tid] = 0;
    if (tid < 256) { m_hi16[tid] = 0; m_lo16[tid] = 0; mf[tid] = 0.f; }
    if (tid < 12) ufrag[tid] = 0.f;
    const float ie0 = ie[0];

    // ---- weights into registers, pinned with asm fences ----
    u32 hk_w[64];
    #pragma unroll
    for (int i = 0; i < 64; ++i)
        hk_w[i] = hk2[(size_t)(64 * kg + i) * 512 + 128 * q + cl];
    u32 amk_w[32];
    #pragma unroll
    for (int i = 0; i < 32; ++i)
        amk_w[i] = amk2[(size_t)(32 * kg + i) * 512 + 128 * q + cl];
    float at_w[32];
    #pragma unroll
    for (int i = 0; i < 32; ++i)
        at_w[i] = at[(size_t)(32 * kg8 + i) * 256 + J];
    #pragma unroll
    for (int i = 0; i < 64; ++i) asm volatile("" : "+v"(hk_w[i]));
    #pragma unroll
    for (int i = 0; i < 32; ++i) asm volatile("" : "+v"(amk_w[i]));
    #pragma unroll
    for (int i = 0; i < 32; ++i) asm volatile("" : "+v"(at_w[i]));

    __syncthreads();

    const uint4*  h4   = reinterpret_cast<const uint4*>(h_h16);    // 64 uint4
    const uint4*  mh4  = reinterpret_cast<const uint4*>(m_hi16);   // 32 uint4
    const uint4*  ml4  = reinterpret_cast<const uint4*>(m_lo16);
    const float4* mfv4 = reinterpret_cast<const float4*>(mf);      // 64 float4
    const float4* ufv4 = reinterpret_cast<const float4*>(ufrag);
    float* outb = out + (size_t)b * N_T * N_UNITS;

    float mreg = 0.f;   // own m value (wave 2: J <-> thread bijection)

    for (int t = 0; t < N_T; ++t) {
        // ---- consume peers' packets → stage to LDS ----
        if (t > 0 && tid < 198) {
            const u32 ep  = (u32)t;
            const int par = (t - 1) & 1;
            if (tid < 192) {
                int pi = tid >> 6, i = tid & 63;
                int q2 = pi + (pi >= q ? 1 : 0);
                const u32* base = pkt + (size_t)(par * 256 + b * 4 + q2) * PKT_STRIDE;
                u32 d0, d1, d2, d3;
                if (i < 32) {                         // m: hi/lo dword pairs
                    const u32* p4 = base + 4 * i;
                    for (;;) {
                        d0 = aload(p4 + 0); d1 = aload(p4 + 1);
                        d2 = aload(p4 + 2); d3 = aload(p4 + 3);
                        if (((((d0 >> 16) ^ ep) | ((d1 >> 16) ^ ep)) |
                             (((d2 >> 16) ^ ep) | ((d3 >> 16) ^ ep))) == 0) break;
                    }
                    int w = 32 * q2 + i;
                    *reinterpret_cast<float2*>(&mf[2 * w]) =
                        make_float2(hbits2f(d0) + hbits2f(d1),
                                    hbits2f(d2) + hbits2f(d3));
                    reinterpret_cast<u32*>(m_hi16)[w] = (d0 & 0xFFFFu) | (d2 << 16);
                    reinterpret_cast<u32*>(m_lo16)[w] = (d1 & 0xFFFFu) | (d3 << 16);
                } else {                              // h: 4 values → 2 dwords
                    const u32* p4 = base + 128 + 4 * (i - 32);
                    for (;;) {
                        d0 = aload(p4 + 0); d1 = aload(p4 + 1);
                        d2 = aload(p4 + 2); d3 = aload(p4 + 3);
                        if (((((d0 >> 16) ^ ep) | ((d1 >> 16) ^ ep)) |
                             (((d2 >> 16) ^ ep) | ((d3 >> 16) ^ ep))) == 0) break;
                    }
                    int w = 64 * q2 + 2 * (i - 32);
                    uint2 hv;
                    hv.x = (d0 & 0xFFFFu) | (d1 << 16);
                    hv.y = (d2 & 0xFFFFu) | (d3 << 16);
                    *reinterpret_cast<uint2*>(&reinterpret_cast<u32*>(h_h16)[w]) = hv;
                }
            } else {                                  // u fragments
                int r = tid - 192;                    // 0..5
                int pi = r >> 1, sub = r & 1;
                int q2 = pi + (pi >= q ? 1 : 0);
                const u32* base =
                    pkt + (size_t)(par * 256 + b * 4 + q2) * PKT_STRIDE + 256;
                if (sub == 0) {
                    u32 d0, d1, d2, d3;
                    for (;;) {
                        d0 = aload(base + 0); d1 = aload(base + 1);
                        d2 = aload(base + 2); d3 = aload(base + 3);
                        if (((((d0 >> 16) ^ ep) | ((d1 >> 16) ^ ep)) |
                             (((d2 >> 16) ^ ep) | ((d3 >> 16) ^ ep))) == 0) break;
                    }
                    ufrag[3 * q2 + 0] = hbits2f(d0) + hbits2f(d1);
                    ufrag[3 * q2 + 1] = hbits2f(d2) + hbits2f(d3);
                } else {
                    u32 d0, d1;
                    for (;;) {
                        d0 = aload(base + 4); d1 = aload(base + 5);
                        if ((((d0 >> 16) ^ ep) | ((d1 >> 16) ^ ep)) == 0) break;
                    }
                    ufrag[3 * q2 + 2] = hbits2f(d0) + hbits2f(d1);
                }
            }
        }
        __syncthreads();                                   // B1

        // ---- u from 12 fragments (b128 broadcast reads) ----
        float u;
        {
            float4 fa = ufv4[0], fb = ufv4[1], fc = ufv4[2];
            u = ((fa.x + fa.y) + (fa.z + fa.w)) + ((fb.x + fb.y) + (fb.z + fb.w))
              + ((fc.x + fc.y) + (fc.z + fc.w)) + xs[t] * ie0;
        }

        // ---- z partials (old h, old m) + AT partials (old m) ----
        {
            float z0 = 0.f, z1 = 0.f, z2 = 0.f, z3 = 0.f;
            #pragma unroll
            for (int j = 0; j < 16; ++j) {
                uint4 hv = h4[16 * kg + j];
                z0 = dot2f(hv.x, hk_w[4 * j + 0], z0);
                z1 = dot2f(hv.y, hk_w[4 * j + 1], z1);
                z2 = dot2f(hv.z, hk_w[4 * j + 2], z2);
                z3 = dot2f(hv.w, hk_w[4 * j + 3], z3);
            }
            #pragma unroll
            for (int j = 0; j < 8; ++j) {
                uint4 mh = mh4[8 * kg + j];
                uint4 ml = ml4[8 * kg + j];
                z0 = dot2f(mh.x, amk_w[4 * j + 0], z0);
                z1 = dot2f(mh.y, amk_w[4 * j + 1], z1);
                z2 = dot2f(mh.z, amk_w[4 * j + 2], z2);
                z3 = dot2f(mh.w, amk_w[4 * j + 3], z3);
                z0 = dot2f(ml.x, amk_w[4 * j + 0], z0);
                z1 = dot2f(ml.y, amk_w[4 * j + 1], z1);
                z2 = dot2f(ml.z, amk_w[4 * j + 2], z2);
                z3 = dot2f(ml.w, amk_w[4 * j + 3], z3);
            }
            zbuf[tid] = (z0 + z1) + (z2 + z3);
            float a0 = 0.f, a1 = 0.f;
            #pragma unroll
            for (int j = 0; j < 8; ++j) {
                float4 mv = mfv4[8 * kg8 + j];
                a0 = fmaf(mv.x, at_w[4 * j + 0], a0);
                a1 = fmaf(mv.y, at_w[4 * j + 1], a1);
                a0 = fmaf(mv.z, at_w[4 * j + 2], a0);
                a1 = fmaf(mv.w, at_w[4 * j + 3], a1);
            }
            ampart[tid] = a0 + a1;
        }
        __syncthreads();                                   // B2

        // ---- finalize (parallel: waves 0-1 = h, wave 2 = m) ----
        const bool pub = (t < N_T - 1);
        const u32 eph = (u32)(t + 1) << 16;
        u32* myb = pkt + (size_t)((t & 1) * 256 + b * 4 + q) * PKT_STRIDE;

        if (tid < 128) {
            float zf = zbuf[tid] + zbuf[tid + 128] + zbuf[tid + 256] + zbuf[tid + 384]
                     + xs[t] * ik_sl[tid] + u * bmk_sl[tid];
            float hnew = tanh_fast(zf);
            u16 hb = f2h_bits(hnew);
            if (pub) astore(myb + 128 + tid, (u32)hb | eph);
            h_h16[128 * q + tid] = hb;
            outb[(size_t)t * N_UNITS + 128 * q + tid] = hnew;
            // u fragment (per wave 0/1)
            float up = hnew * he_sl[tid];
            #pragma unroll
            for (int off = 32; off > 0; off >>= 1) up += __shfl_down(up, off);
            if (lane == 0) {
                int w = tid >> 6;
                ufrag[3 * q + w] = up;
                if (pub) {
                    _Float16 hi = (_Float16)up;
                    float lo = up - (float)hi;
                    astore(myb + 256 + 2 * w,     (u32)__builtin_bit_cast(u16, hi) | eph);
                    astore(myb + 256 + 2 * w + 1, (u32)f2h_bits(lo) | eph);
                }
            }
        } else if (tid < 192) {
            float mnew = mreg + u * bt_sl[jl];
            #pragma unroll
            for (int gi = 0; gi < 8; ++gi) mnew += ampart[jl + 64 * gi];
            mreg = mnew;
            _Float16 hi = (_Float16)mnew;
            float lo = mnew - (float)hi;
            u16 hib = __builtin_bit_cast(u16, hi), lob = f2h_bits(lo);
            mf[J] = mnew;
            m_hi16[J] = hib;
            m_lo16[J] = lob;
            if (pub) {
                astore(myb + 2 * jl,     (u32)hib | eph);
                astore(myb + 2 * jl + 1, (u32)lob | eph);
            }
            // u fragment (wave 2): m·me
            float up = mnew * me_sl[jl];
            #pragma unroll
            for (int off = 32; off > 0; off >>= 1) up += __shfl_down(up, off);
            if (lane == 0) {
                ufrag[3 * q + 2] = up;
                if (pub) {
                    _Float16 uhi = (_Float16)up;
                    float ulo = up - (float)uhi;
                    astore(myb + 260, (u32)__builtin_bit_cast(u16, uhi) | eph);
                    astore(myb + 261, (u32)f2h_bits(ulo) | eph);
                }
            }
        }
        // B1 of next iteration orders finalize writes vs z-phase reads.
    }
}

extern "C" void kernel_launch(void* const* d_in, const int* in_sizes, int n_in,
                              void* d_out, int out_size, void* d_ws, size_t ws_size,
                              hipStream_t stream) {
    const float* x  = (const float*)d_in[0];
    const float* ie = (const float*)d_in[1];
    const float* he = (const float*)d_in[2];
    const float* me = (const float*)d_in[3];
    const float* ik = (const float*)d_in[4];
    const float* hk = (const float*)d_in[5];
    const float* mk = (const float*)d_in[6];
    const float* at = (const float*)d_in[7];
    const float* bt = (const float*)d_in[8];

    u32*   hk2  = (u32*)d_ws;                   // 131072 u32 = 512 KB
    u32*   amk2 = hk2 + 256 * 512;              //  65536 u32 = 256 KB
    float* bmk  = (float*)(amk2 + 128 * 512);   //    512 f32 =   2 KB
    u32*   pkt  = (u32*)(bmk + 512);            // 2*64*4*288 u32 = 576 KB

    prep_hk<<<512, 256, 0, stream>>>(hk, hk2);
    prep_amk<<<129, 512, 0, stream>>>(mk, at, bt, amk2, bmk);
    lmu_main<<<N_B * KWG, 512, 0, stream>>>(x, ie, he, me, ik, bt, at,
                                            hk2, amk2, bmk, pkt, (float*)d_out);
}